// Round 6
// baseline (2083.840 us; speedup 1.0000x reference)
//
#include <hip/hip_runtime.h>
#include <hip/hip_bf16.h>

#define LAT 128
#define H 256
#define OUTD 64
#define SEQ 512

typedef short bf16x8 __attribute__((ext_vector_type(8)));
typedef float f32x4  __attribute__((ext_vector_type(4)));
typedef unsigned long long u64;
typedef unsigned u32;

__device__ __forceinline__ float sigm(float x)  { return 1.f / (1.f + __expf(-x)); }
__device__ __forceinline__ float tanhf_(float x){ return 1.f - 2.f / (__expf(2.f * x) + 1.f); }

__device__ __forceinline__ short f2bs(float x) {
    __hip_bfloat16 b = __float2bfloat16(x);
    return *reinterpret_cast<short*>(&b);
}
__device__ __forceinline__ float bs2f(unsigned short h) {
    u32 b = ((u32)h) << 16;
    float f; __builtin_memcpy(&f, &b, 4); return f;
}
__device__ __forceinline__ u32 f2pair(float a, float b) {
    return ((u32)(unsigned short)f2bs(b) << 16) | (u32)(unsigned short)f2bs(a);
}
__device__ __forceinline__ bf16x8 pack8(const float* s) {
    bf16x8 v;
    v[0]=f2bs(s[0]); v[1]=f2bs(s[1]); v[2]=f2bs(s[2]); v[3]=f2bs(s[3]);
    v[4]=f2bs(s[4]); v[5]=f2bs(s[5]); v[6]=f2bs(s[6]); v[7]=f2bs(s[7]);
    return v;
}

// ---- Transport: AGENT scope (R5-proven neutral-or-better vs system).
// R1/R4/R5 established: scope, RMW, and store/load vmcnt coupling are all
// ~neutral -> transport latency class is NOT the period driver. R6 attacks
// the remaining term: per-cluster fan-in (convoy across producer wgs) and
// per-CU compute density, by halving wgs-per-cluster (16 -> 8).
__device__ __forceinline__ u64 sys_load_u64(const u64* p) {
    return __hip_atomic_load((u64*)p, __ATOMIC_RELAXED, __HIP_MEMORY_SCOPE_AGENT);
}
__device__ __forceinline__ void sys_store_u64(u64* p, u64 v) {
    __hip_atomic_store(p, v, __ATOMIC_RELAXED, __HIP_MEMORY_SCOPE_AGENT);
}

// ---------------- Prologue 1 (round-8 verbatim): tagged h-init, c-init, L1 bias ----
__global__ void lstm_prologue_init(const float* __restrict__ z,
                                   const float* __restrict__ Whid,
                                   const float* __restrict__ bhid,
                                   const float* __restrict__ Wcell,
                                   const float* __restrict__ bcell,
                                   const float* __restrict__ bih1,
                                   const float* __restrict__ bhh1,
                                   u64* __restrict__ h0B1,
                                   u64* __restrict__ h1B1,
                                   float* __restrict__ c0,
                                   float* __restrict__ c1,
                                   float* __restrict__ gxb1)
{
    int t = blockIdx.x * 256 + threadIdx.x;
    if (t < 65536) {                     // tagged hidden-init: 2 layers x 256 b x 128 pairs
        int layer = t >> 15;
        int tt = t & 32767;
        int b = tt >> 7, cp = tt & 127;
        int colA = layer * H + 2 * cp;
        const float* zr = z + b * LAT;
        const float* wA = Whid + colA * LAT;
        const float* wB = wA + LAT;
        float a0 = bhid[colA], a1 = bhid[colA + 1];
        for (int k = 0; k < LAT; k++) { float zv = zr[k]; a0 += zv * wA[k]; a1 += zv * wB[k]; }
        u64 v = ((u64)(u32)layer << 32) | (u64)f2pair(a0, a1);
        (layer ? h1B1 : h0B1)[b * 128 + cp] = v;
    } else if (t < 196608) {             // cell init: [256 x 512]
        int tt = t - 65536;
        int b = tt >> 9, col = tt & 511;
        const float* w  = Wcell + col * LAT;
        const float* zr = z + b * LAT;
        float acc = bcell[col];
        for (int k = 0; k < LAT; k++) acc += zr[k] * w[k];
        if (col < H) c0[b * H + col] = acc;
        else         c1[b * H + (col - H)] = acc;
    } else if (t < 197632) {             // layer-1 gate bias vector [1024]
        int g = t - 196608;
        gxb1[g] = bih1[g] + bhh1[g];
    }
}

// ---------------- Prologue 2 (round-8 verbatim): gx0 packed bf16 pairs ----
__global__ void lstm_prologue_gx0(const float* __restrict__ z,
                                  const float* __restrict__ Win,
                                  const float* __restrict__ bin,
                                  const float* __restrict__ Wih0,
                                  const float* __restrict__ bih0,
                                  const float* __restrict__ bhh0,
                                  u32* __restrict__ gxb0u)
{
    __shared__ float xs[H];
    const int b = blockIdx.y;
    const int tid = threadIdx.x;
    {
        const float* w  = Win + tid * LAT;
        const float* zr = z + b * LAT;
        float acc = bin[tid];
        for (int k = 0; k < LAT; k++) acc += zr[k] * w[k];
        xs[tid] = acc;
    }
    __syncthreads();
    const int cA = blockIdx.x * 512 + 2 * tid;
    const float* wA = Wih0 + cA * H;
    const float* wB = wA + H;
    float a0 = bih0[cA]     + bhh0[cA];
    float a1 = bih0[cA + 1] + bhh0[cA + 1];
    for (int k = 0; k < H; k++) { float xv = xs[k]; a0 += xv * wA[k]; a1 += xv * wB[k]; }
    gxb0u[b * 512 + blockIdx.x * 256 + tid] = f2pair(a0, a1);
}

// ---------------- Persistent kernel ----------------
// R6 GEOMETRY: 128 wgs x 256 thr. Cluster bg = wg>>3 (16 clusters x 16 batch
// rows); wg j = wg&7 owns 32 hidden cols (2 m-tiles per wave, t in {0,1};
// col = j*32 + wave*8 + t*4 + q). Halves the all-to-all fan-in (8 producers)
// and doubles per-wg compute (MFMA issue ~930cy/step/wave vs 19.4cy/inst
// SIMD throughput), so transport/convoy hides under compute.
// Transport protocol, poll positions, snapshot spins, sched_barrier pins,
// LDS layout, workspace: verbatim R5. Weights per thread: wf[3][2][8]
// (~192 VGPRs); 1 wg/CU -> 512-VGPR budget, no spill expected.
__global__ __launch_bounds__(256, 1)
void lstm_persistent(const u32* __restrict__ gxb0u, const float* __restrict__ gxb1,
                     const float* __restrict__ c0g, const float* __restrict__ c1g,
                     u64* __restrict__ h0B0, u64* __restrict__ h0B1,
                     u64* __restrict__ h1B0, u64* __restrict__ h1B1,
                     const float* __restrict__ Whh0, const float* __restrict__ Wih1,
                     const float* __restrict__ Whh1, const float* __restrict__ Wout,
                     const float* __restrict__ bout, float* __restrict__ out)
{
    const int wg = blockIdx.x;
    const int bg = wg >> 3;
    const int j  = wg & 7;
    const int tid  = threadIdx.x;
    const int wave = tid >> 6;
    const int q  = (tid >> 4) & 3;
    const int ln = tid & 15;
    const int myb   = bg * 16 + ln;

    __shared__ u32 hs0[2][16 * 132];           // parity planes, row-major packed pairs
    __shared__ u32 hs1[2][16 * 132];

    // ---- A-frags: packed-gate weight rows (m = c*4 + g), 2 m-tiles/wave ----
    bf16x8 wf[3][2][8];
    {
        const float* mats[3] = { Whh0, Wih1, Whh1 };
        #pragma unroll
        for (int mm = 0; mm < 3; mm++) {
            #pragma unroll
            for (int t = 0; t < 2; t++) {
                const int arow = (ln & 3) * H + j * 32 + wave * 8 + t * 4 + (ln >> 2);
                const float* s = mats[mm] + arow * H;
                #pragma unroll
                for (int kk = 0; kk < 8; kk++) wf[mm][t][kk] = pack8(s + kk * 32 + q * 8);
            }
        }
    }
    const bool doOut = (j < 4) && (wave == 0);
    bf16x8 wo[8];
    float bor[4] = {0.f, 0.f, 0.f, 0.f};
    if (doOut) {
        const int orow = j * 16 + ln;          // natural rows: C m = out-col
        const float* s = Wout + orow * H;
        #pragma unroll
        for (int kk = 0; kk < 8; kk++) wo[kk] = pack8(s + kk * 32 + q * 8);
        #pragma unroll
        for (int r = 0; r < 4; r++) bor[r] = bout[j * 16 + q * 4 + r];
    }

    // ---- per-lane gate biases + cell state (per m-tile t) ----
    float gxr0[2][4], gxr1[2][4];
    float creg0[2], creg1[2];
    #pragma unroll
    for (int t = 0; t < 2; t++) {
        const int colt = j * 32 + wave * 8 + t * 4 + q;
        #pragma unroll
        for (int r = 0; r < 4; r++) {
            u32 v = gxb0u[myb * 512 + ((r * 256 + colt) >> 1)];
            gxr0[t][r] = bs2f((unsigned short)((colt & 1) ? (v >> 16) : (v & 0xFFFFu)));
            gxr1[t][r] = gxb1[r * 256 + colt];
        }
        creg0[t] = c0g[myb * H + colt];
        creg1[t] = c1g[myb * H + colt];
    }

    u64* A0 = h0B0 + bg * 2048;   // cluster slices: 16 rows x 128 pair-slots
    u64* A1 = h0B1 + bg * 2048;
    u64* B0 = h1B0 + bg * 2048;
    u64* B1 = h1B1 + bg * 2048;

    // pair slot for tile t: col/2 = j*16 + wave*4 + t*2 + q/2 (even-q lanes)
    const int pubbase = ln * 128 + j * 16 + wave * 4 + (q >> 1);
    const bool pubLane = ((q & 1) == 0);

    // ---- carried h0 poll regs; preloop: k=0 snapshot from A1 (prologue tag 0) ----
    u64 v0[8];
    #pragma unroll
    for (int i = 0; i < 8; i++) v0[i] = sys_load_u64(A1 + i * 256 + tid);

    for (int k = 0; k <= SEQ + 1; k++) {
        const u64* P1 = (k & 1) ? B1 : B0;  u64* C1 = (k & 1) ? B0 : B1;
        u64* C0 = (k & 1) ? A1 : A0;
        const int par = k & 1;

        // ---- TOP staging: h0 (carried snapshot check; reload-all fallback) ----
        if (k <= SEQ) {
            const u64* P0 = (k & 1) ? A0 : A1;
            bool ok = true;
            #pragma unroll
            for (int i = 0; i < 8; i++) ok = ok && ((u32)(v0[i] >> 32) == (u32)k);
            int guard = 0;
            while (!ok && guard < 16384) {
                ok = true;
                #pragma unroll
                for (int i = 0; i < 8; i++) v0[i] = sys_load_u64(P0 + i * 256 + tid);
                #pragma unroll
                for (int i = 0; i < 8; i++) ok = ok && ((u32)(v0[i] >> 32) == (u32)k);
                guard++;
            }
            u32* dst = hs0[par];
            #pragma unroll
            for (int i = 0; i < 8; i++) { int s = i * 256 + tid; dst[(s >> 7) * 132 + (s & 127)] = (u32)v0[i]; }
        }
        __syncthreads();                       // B1

        // ---- h0 B-frags (batch row ln) ----
        bf16x8 hb0[8];
        {
            const unsigned short* b0p = (const unsigned short*)hs0[par];
            #pragma unroll
            for (int kk = 0; kk < 8; kk++)
                hb0[kk] = *(const bf16x8*)(b0p + ln * 264 + kk * 32 + q * 8);
        }

        // ---- issue h1 tag-k poll loads NOW (slack ~0.7T; hide under L0;
        //      older than the L0 publish store -> check excludes store ack) ----
        u64 v1[8];
        if (k >= 1) {
            #pragma unroll
            for (int i = 0; i < 8; i++) v1[i] = sys_load_u64(P1 + i * 256 + tid);
        }
        __builtin_amdgcn_sched_barrier(0);     // pin: loads issued before L0 block

        // ---- layer 0, step k: 2 m-tiles, independent acc chains ----
        if (k < SEQ) {
            f32x4 acc0 = {0.f, 0.f, 0.f, 0.f};
            f32x4 acc1 = {0.f, 0.f, 0.f, 0.f};
            #pragma unroll
            for (int kk = 0; kk < 8; kk++) {
                acc0 = __builtin_amdgcn_mfma_f32_16x16x32_bf16(wf[0][0][kk], hb0[kk], acc0, 0, 0, 0);
                acc1 = __builtin_amdgcn_mfma_f32_16x16x32_bf16(wf[0][1][kk], hb0[kk], acc1, 0, 0, 0);
            }
            u32 pa[2];
            #pragma unroll
            for (int t = 0; t < 2; t++) {
                const f32x4 acc = t ? acc1 : acc0;
                float i_ = sigm(acc[0] + gxr0[t][0]);
                float f_ = sigm(acc[1] + gxr0[t][1]);
                float g_ = tanhf_(acc[2] + gxr0[t][2]);
                float o_ = sigm(acc[3] + gxr0[t][3]);
                creg0[t] = f_ * creg0[t] + i_ * g_;
                int us = (int)(u32)(unsigned short)f2bs(o_ * tanhf_(creg0[t]));
                int other = __shfl_xor(us, 16);    // q <-> q^1 (col pair partner)
                pa[t] = (u32)us | ((u32)other << 16);
            }
            if (pubLane) {
                sys_store_u64(C0 + pubbase + 0, ((u64)(u32)(k + 1) << 32) | (u64)pa[0]);
                sys_store_u64(C0 + pubbase + 2, ((u64)(u32)(k + 1) << 32) | (u64)pa[1]);
            }
        }

        // ---- MID staging: h1 (check prefetched snapshot; reload-all fallback) ----
        if (k >= 1) {
            bool ok = true;
            #pragma unroll
            for (int i = 0; i < 8; i++) ok = ok && ((u32)(v1[i] >> 32) == (u32)k);
            int guard = 0;
            while (!ok && guard < 16384) {
                ok = true;
                #pragma unroll
                for (int i = 0; i < 8; i++) v1[i] = sys_load_u64(P1 + i * 256 + tid);
                #pragma unroll
                for (int i = 0; i < 8; i++) ok = ok && ((u32)(v1[i] >> 32) == (u32)k);
                guard++;
            }
            u32* dst = hs1[par];
            #pragma unroll
            for (int i = 0; i < 8; i++) { int s = i * 256 + tid; dst[(s >> 7) * 132 + (s & 127)] = (u32)v1[i]; }
        }
        __syncthreads();                       // B2

        // ---- h1 B-frags ----
        bf16x8 hb1[8];
        {
            const unsigned short* b1p = (const unsigned short*)hs1[par];
            #pragma unroll
            for (int kk = 0; kk < 8; kk++)
                hb1[kk] = *(const bf16x8*)(b1p + ln * 264 + kk * 32 + q * 8);
        }

        // ---- layer 1, step k-1: 2 m-tiles x 2 input matrices = 4 acc chains ----
        u32 pa1[2]; bool pub1 = false;
        if (k >= 1 && k <= SEQ) {
            f32x4 accA0 = {0.f, 0.f, 0.f, 0.f};
            f32x4 accB0 = {0.f, 0.f, 0.f, 0.f};
            f32x4 accA1 = {0.f, 0.f, 0.f, 0.f};
            f32x4 accB1 = {0.f, 0.f, 0.f, 0.f};
            #pragma unroll
            for (int kk = 0; kk < 8; kk++) {
                accA0 = __builtin_amdgcn_mfma_f32_16x16x32_bf16(wf[1][0][kk], hb0[kk], accA0, 0, 0, 0);
                accB0 = __builtin_amdgcn_mfma_f32_16x16x32_bf16(wf[2][0][kk], hb1[kk], accB0, 0, 0, 0);
                accA1 = __builtin_amdgcn_mfma_f32_16x16x32_bf16(wf[1][1][kk], hb0[kk], accA1, 0, 0, 0);
                accB1 = __builtin_amdgcn_mfma_f32_16x16x32_bf16(wf[2][1][kk], hb1[kk], accB1, 0, 0, 0);
            }
            #pragma unroll
            for (int t = 0; t < 2; t++) {
                const f32x4 aA = t ? accA1 : accA0;
                const f32x4 aB = t ? accB1 : accB0;
                float i_ = sigm(aA[0] + aB[0] + gxr1[t][0]);
                float f_ = sigm(aA[1] + aB[1] + gxr1[t][1]);
                float g_ = tanhf_(aA[2] + aB[2] + gxr1[t][2]);
                float o_ = sigm(aA[3] + aB[3] + gxr1[t][3]);
                creg1[t] = f_ * creg1[t] + i_ * g_;
                int us = (int)(u32)(unsigned short)f2bs(o_ * tanhf_(creg1[t]));
                int other = __shfl_xor(us, 16);
                pa1[t] = (u32)us | ((u32)other << 16);
            }
            pub1 = pubLane;
        }

        // ---- LATE h0 prefetch for k+1 (published at ~0.4T this iter by all
        //      wgs). Issued BEFORE the L1 publish store so the top-of-(k+1)
        //      check's counted vmcnt excludes the store ack. ----
        if (k < SEQ) {
            #pragma unroll
            for (int i = 0; i < 8; i++) v0[i] = sys_load_u64(C0 + i * 256 + tid);
        }
        __builtin_amdgcn_sched_barrier(0);     // pin: prefetch before publish store

        // ---- layer-1 publish (stores younger than all poll loads) ----
        if (pub1) {
            sys_store_u64(C1 + pubbase + 0, ((u64)(u32)(k + 1) << 32) | (u64)pa1[0]);
            sys_store_u64(C1 + pubbase + 2, ((u64)(u32)(k + 1) << 32) | (u64)pa1[1]);
        }

        // ---- output projection, step k-2 (reuses hb1 = h1_{k-2}); f32x4 store ----
        if (k >= 2 && doOut) {
            f32x4 acc = {0.f, 0.f, 0.f, 0.f};
            #pragma unroll
            for (int kk = 0; kk < 8; kk++)
                acc = __builtin_amdgcn_mfma_f32_16x16x32_bf16(wo[kk], hb1[kk], acc, 0, 0, 0);
            f32x4 res;
            #pragma unroll
            for (int r = 0; r < 4; r++) res[r] = acc[r] + bor[r];
            *(f32x4*)&out[(bg * 16 + ln) * (SEQ * OUTD) + (k - 2) * OUTD + j * 16 + q * 4] = res;
        }
    }
}

extern "C" void kernel_launch(void* const* d_in, const int* in_sizes, int n_in,
                              void* d_out, int out_size, void* d_ws, size_t ws_size,
                              hipStream_t stream) {
    const float* z     = (const float*)d_in[0];
    const float* Whid  = (const float*)d_in[1];
    const float* bhid  = (const float*)d_in[2];
    const float* Wcell = (const float*)d_in[3];
    const float* bcell = (const float*)d_in[4];
    const float* Win   = (const float*)d_in[5];
    const float* bin   = (const float*)d_in[6];
    const float* Wih0  = (const float*)d_in[7];
    const float* Whh0  = (const float*)d_in[8];
    const float* bih0  = (const float*)d_in[9];
    const float* bhh0  = (const float*)d_in[10];
    const float* Wih1  = (const float*)d_in[11];
    const float* Whh1  = (const float*)d_in[12];
    const float* bih1  = (const float*)d_in[13];
    const float* bhh1  = (const float*)d_in[14];
    const float* Wout  = (const float*)d_in[15];
    const float* bout  = (const float*)d_in[16];
    float* out = (float*)d_out;

    // workspace: 2,101,248 B total (== round-8-proven size)
    u32*   gxb0u = (u32*)d_ws;                   // [131072] bf16-pair gate biases
    float* gxb1  = (float*)(gxb0u + 131072);     // [1024]
    float* c0    = gxb1 + 1024;                  // [65536]
    float* c1    = c0 + 65536;                   // [65536]
    u64*   h0B0  = (u64*)(c1 + 65536);           // [32768] tagged pair-slots x4
    u64*   h0B1  = h0B0 + 32768;
    u64*   h1B0  = h0B1 + 32768;
    u64*   h1B1  = h1B0 + 32768;

    lstm_prologue_init<<<772, 256, 0, stream>>>(z, Whid, bhid, Wcell, bcell,
                                                bih1, bhh1, h0B1, h1B1, c0, c1, gxb1);
    lstm_prologue_gx0<<<dim3(2, 256), 256, 0, stream>>>(z, Win, bin, Wih0, bih0, bhh0, gxb0u);

    void* kargs[] = { (void*)&gxb0u, (void*)&gxb1, (void*)&c0, (void*)&c1,
                      (void*)&h0B0, (void*)&h0B1, (void*)&h1B0, (void*)&h1B1,
                      (void*)&Whh0, (void*)&Wih1, (void*)&Whh1, (void*)&Wout,
                      (void*)&bout, (void*)&out };
    hipError_t ce = hipLaunchCooperativeKernel((const void*)lstm_persistent,
                                               dim3(128), dim3(256), kargs, 0, stream);
    if (ce != hipSuccess) {
        lstm_persistent<<<128, 256, 0, stream>>>(gxb0u, gxb1, c0, c1,
                                                 h0B0, h0B1, h1B0, h1B1,
                                                 Whh0, Wih1, Whh1, Wout, bout, out);
    }
}